// Round 1
// baseline (928.263 us; speedup 1.0000x reference)
//
#include <hip/hip_runtime.h>
#include <stdint.h>

// HashGrid forward: instant-NGP multiresolution hash encoding.
// N=2^21 points, 16 levels x 2 features, T=2^19 entries/level, fp32.
//
// thread = n*16 + l  (one thread per point-level pair)
//   -> out offset = n*32 + l*2 = 2*tid  (perfectly coalesced float2 stores)
//   -> 16 consecutive threads share one x[n] cache line
//
// Correctness-critical: pos = x*scale + 0.5 must be separate fp32 mul/add
// (reference numpy semantics). FMA contraction could flip floor(pos) at a
// cell boundary -> wrong gather -> ~1e-4 error vs 2e-6 threshold. Pinned
// with __fmul_rn/__fadd_rn.

constexpr int      kNPoints = 2097152;
constexpr int      kNLevels = 16;
constexpr uint32_t kT       = 524288u;      // 2^19
constexpr uint32_t kTMask   = kT - 1u;
constexpr uint32_t kPrimeY  = 2654435761u;  // tcnn 2D spatial-hash prime

__global__ __launch_bounds__(256) void hashgrid_fwd(
    const float* __restrict__ x,
    const float* __restrict__ table,
    float* __restrict__ out)
{
    // Per-level constants. scale = 16*1.5^l - 1 is exactly fp32-representable
    // for all l (checked: numerator < 2^24 over pow2 denominator).
    __shared__ float    s_scale[16];
    __shared__ uint32_t s_res[16];
    if (threadIdx.x < 16) {
        const float ksc[16] = {
            15.0f, 23.0f, 35.0f, 53.0f, 80.0f, 120.5f, 181.25f, 272.375f,
            409.0625f, 614.09375f, 921.640625f, 1382.9609375f,
            2074.94140625f, 3112.912109375f, 4669.8681640625f, 7005.30224609375f};
        const uint32_t kre[16] = {16u, 24u, 36u, 54u, 81u, 122u, 183u, 274u,
                                  411u, 616u, 923u, 1384u, 2076u, 3114u, 4671u, 7007u};
        s_scale[threadIdx.x] = ksc[threadIdx.x];
        s_res[threadIdx.x]   = kre[threadIdx.x];
    }
    __syncthreads();

    const uint32_t tid = blockIdx.x * blockDim.x + threadIdx.x;
    const uint32_t l   = tid & 15u;
    const uint32_t n   = tid >> 4;

    const float2   xy    = reinterpret_cast<const float2*>(x)[n];
    const float    scale = s_scale[l];
    const uint32_t res   = s_res[l];
    const bool     dense = (l < 10u);   // res*res <= T for levels 0..9

    // pos = x*scale + 0.5, separate rounding steps (no FMA contraction)
    const float px  = __fadd_rn(__fmul_rn(xy.x, scale), 0.5f);
    const float py  = __fadd_rn(__fmul_rn(xy.y, scale), 0.5f);
    const float fpx = floorf(px);
    const float fpy = floorf(py);
    const float fx  = px - fpx;   // interpolation fractions
    const float fy  = py - fpy;
    const uint32_t gx = (uint32_t)fpx;
    const uint32_t gy = (uint32_t)fpy;

    const float2* __restrict__ tab =
        reinterpret_cast<const float2*>(table) + ((size_t)l << 19);  // level base (T float2s per level)

    float ax = 0.0f, ay = 0.0f;
#pragma unroll
    for (int dx = 0; dx < 2; ++dx) {
        const uint32_t cx = gx + (uint32_t)dx;
        const float    wx = dx ? fx : (1.0f - fx);
#pragma unroll
        for (int dy = 0; dy < 2; ++dy) {
            const uint32_t cy = gy + (uint32_t)dy;
            const float    wy = dy ? fy : (1.0f - fy);
            // branchless dense/hash select (wave holds both kinds of lanes)
            const uint32_t idx_d = (cx + cy * res) & kTMask;
            const uint32_t idx_h = (cx ^ (cy * kPrimeY)) & kTMask;
            const uint32_t idx   = dense ? idx_d : idx_h;
            const float2   v     = tab[idx];
            const float    w     = wx * wy;
            ax = fmaf(v.x, w, ax);
            ay = fmaf(v.y, w, ay);
        }
    }
    reinterpret_cast<float2*>(out)[tid] = make_float2(ax, ay);
}

extern "C" void kernel_launch(void* const* d_in, const int* in_sizes, int n_in,
                              void* d_out, int out_size, void* d_ws, size_t ws_size,
                              hipStream_t stream) {
    const float* x     = (const float*)d_in[0];
    const float* table = (const float*)d_in[1];
    float*       out   = (float*)d_out;
    const int total_threads = kNPoints * kNLevels;   // 33,554,432
    hashgrid_fwd<<<total_threads / 256, 256, 0, stream>>>(x, table, out);
}